// Round 5
// baseline (477.154 us; speedup 1.0000x reference)
//
#include <hip/hip_runtime.h>
#include <hip/hip_bf16.h>

#define BB 8
#define NN 16384
#define DD 1024
#define AA 128
#define CHUNK 32                  // rows per fused block
#define NCH (BB * NN / CHUNK)     // 4096 chunks total
#define CPB (NN / CHUNK)          // 512 chunks per bag

typedef __attribute__((ext_vector_type(8))) short bf16x8;
typedef __attribute__((ext_vector_type(4))) float f32x4;
typedef __attribute__((ext_vector_type(4))) unsigned short u16x4;

__device__ __forceinline__ unsigned short f2bf(float x) {
  union { __hip_bfloat16 h; unsigned short u; } cv;
  cv.h = __float2bfloat16(x);
  return cv.u;
}

__device__ __forceinline__ float bf2f(unsigned short u) {
  return __uint_as_float((unsigned int)u << 16);
}

__device__ __forceinline__ float softplusf(float x) {
  return fmaxf(x, 0.f) + log1pf(expf(-fabsf(x)));
}

// order-preserving float->uint map (monotone)
__device__ __forceinline__ unsigned int ordu(float x) {
  unsigned int u = __float_as_uint(x);
  return (u & 0x80000000u) ? ~u : (u | 0x80000000u);
}

// LDS index swizzle for k_select (breaks stride-64-float bank conflicts)
__device__ __forceinline__ int fvx(int i) {
  return i ^ ((i >> 6) & 63);
}

// ---------------------------------------------------------------------------
// Kernel 0: convert+transpose W1 -> W1T (bf16, [A=128][D=1024]); zero out[8..9].
// ---------------------------------------------------------------------------
__global__ __launch_bounds__(256) void k_prep(
    const float* __restrict__ W1, unsigned short* __restrict__ W1T,
    float* __restrict__ out) {
  const int gid = blockIdx.x * 256 + threadIdx.x;
  if (gid == 0) { out[8] = 0.f; out[9] = 0.f; }
  if (gid < DD * AA) {
    const int col = gid >> 10;      // 0..127
    const int k   = gid & 1023;     // 0..1023
    W1T[gid] = f2bf(W1[k * AA + col]);
  }
}

// ---------------------------------------------------------------------------
// Kernel 1 (fused): per 32-row chunk g:
//   - stage X[32][1024] as bf16 in LDS (swizzled), single HBM read of X
//   - f rows via MFMA (B-frags read directly from L2-resident W1T)
//   - block-local softmax partials: m_b, s_b, zp_b[1024] = sum exp(f-m_b)*X
// 8 waves: wave = (wr 0..1)x(wc 0..3) -> 16 rows x 32 cols.
// ---------------------------------------------------------------------------
__global__ __launch_bounds__(512, 4) void k_fused(
    const float* __restrict__ X, const unsigned short* __restrict__ W1T,
    const float* __restrict__ b1, const float* __restrict__ w2,
    const float* __restrict__ b2p, const float* __restrict__ mask,
    float* __restrict__ f, float* __restrict__ mpart,
    float* __restrict__ spart, float* __restrict__ zpart) {
  __shared__ unsigned short Xs[CHUNK * 1024];  // 64 KB, chunk-XOR swizzled
  __shared__ float fpart[4][CHUNK];
  __shared__ float wrow[CHUNK];
  __shared__ float zq[3][1024];                // 12 KB partial z buffers
  const int t = threadIdx.x;
  const int lane = t & 63, wv = t >> 6;
  const int l15 = lane & 15, lg = lane >> 4;
  const int wr = wv >> 2, wc = wv & 3;
  const int g = blockIdx.x;
  const size_t n0 = (size_t)g * CHUNK;
  const float* Xb = X + n0 * DD;

  // ---- stage X tile (f32 -> bf16, swizzled) ----
#pragma unroll
  for (int j = 0; j < 16; ++j) {
    const int i = t + j * 512;        // float4 index, 0..8191
    const int r = i >> 8;             // 256 float4 per row
    const int k = (i & 255) * 4;
    float4 v = *(const float4*)(Xb + (size_t)r * DD + k);
    u16x4 p;
    p.x = f2bf(v.x); p.y = f2bf(v.y); p.z = f2bf(v.z); p.w = f2bf(v.w);
    const int idx = r * 1024 + (((k >> 3) ^ (r & 7)) << 3) + (k & 7);
    *(u16x4*)&Xs[idx] = p;
  }
  __syncthreads();

  // ---- MFMA: 16x32 wave tile, K=1024, no barriers in loop ----
  f32x4 zero4 = {0.f, 0.f, 0.f, 0.f};
  f32x4 acc[2] = {zero4, zero4};
  const int r = wr * 16 + l15;
  const unsigned short* Bp0 = W1T + (size_t)(wc * 32 + l15) * DD;
  const unsigned short* Bp1 = W1T + (size_t)(wc * 32 + 16 + l15) * DD;
#pragma unroll 4
  for (int ks = 0; ks < 32; ++ks) {
    const int c = ks * 4 + lg;
    const bf16x8 af = *(const bf16x8*)&Xs[r * 1024 + ((c ^ (r & 7)) << 3)];
    const bf16x8 b0 = *(const bf16x8*)(Bp0 + c * 8);
    const bf16x8 b1v = *(const bf16x8*)(Bp1 + c * 8);
    acc[0] = __builtin_amdgcn_mfma_f32_16x16x32_bf16(af, b0, acc[0], 0, 0, 0);
    acc[1] = __builtin_amdgcn_mfma_f32_16x16x32_bf16(af, b1v, acc[1], 0, 0, 0);
  }

  // ---- f epilogue: row-partial over this wave's 32 cols ----
  const float b2v = b2p[0];
  float w2c[2], b1c[2];
  w2c[0] = w2[wc * 32 + l15];      b1c[0] = b1[wc * 32 + l15];
  w2c[1] = w2[wc * 32 + 16 + l15]; b1c[1] = b1[wc * 32 + 16 + l15];
#pragma unroll
  for (int q = 0; q < 4; ++q) {
    float s = w2c[0] * tanhf(acc[0][q] + b1c[0]) +
              w2c[1] * tanhf(acc[1][q] + b1c[1]);
    s += __shfl_xor(s, 1);
    s += __shfl_xor(s, 2);
    s += __shfl_xor(s, 4);
    s += __shfl_xor(s, 8);
    if (l15 == 0) fpart[wc][wr * 16 + lg * 4 + q] = s;
  }
  __syncthreads();

  // ---- rows: finish f, local masked max / sum-exp, weights ----
  if (t < CHUNK) {
    const float fr = fpart[0][t] + fpart[1][t] + fpart[2][t] + fpart[3][t] + b2v;
    f[n0 + t] = fr;
    const float mk = mask[n0 + t];
    const float mv = mk > 0.f ? fr : -1.0e30f;
    float mb = mv;
#pragma unroll
    for (int s = 1; s < 32; s <<= 1) mb = fmaxf(mb, __shfl_xor(mb, s));
    const float w = mk > 0.f ? expf(fr - mb) : 0.f;
    wrow[t] = w;
    float sb = w;
#pragma unroll
    for (int s = 1; s < 32; s <<= 1) sb += __shfl_xor(sb, s);
    if (t == 0) { mpart[g] = mb; spart[g] = sb; }
  }
  __syncthreads();

  // ---- z partials: zp[d] = sum_n wrow[n] * X[n][d] from LDS tile ----
  const int c8 = t & 127;           // d-chunk of 8
  const int rg = t >> 7;            // row group: rows rg*8 .. rg*8+7
  float za[8] = {0.f, 0.f, 0.f, 0.f, 0.f, 0.f, 0.f, 0.f};
#pragma unroll
  for (int n = 0; n < 8; ++n) {
    const int rr = rg * 8 + n;
    const float w = wrow[rr];
    const bf16x8 xv = *(const bf16x8*)&Xs[rr * 1024 + ((c8 ^ (rr & 7)) << 3)];
#pragma unroll
    for (int j = 0; j < 8; ++j) za[j] += w * bf2f((unsigned short)xv[j]);
  }
  if (rg > 0) {
#pragma unroll
    for (int j = 0; j < 8; ++j) zq[rg - 1][c8 * 8 + j] = za[j];
  }
  __syncthreads();
  if (rg == 0) {
    float* zp = zpart + ((size_t)g << 10) + c8 * 8;
#pragma unroll
    for (int j = 0; j < 8; ++j)
      za[j] += zq[0][c8 * 8 + j] + zq[1][c8 * 8 + j] + zq[2][c8 * 8 + j];
    *(float4*)(zp) = make_float4(za[0], za[1], za[2], za[3]);
    *(float4*)(zp + 4) = make_float4(za[4], za[5], za[6], za[7]);
  }
}

// ---------------------------------------------------------------------------
// Kernel 2: combine chunk partials -> zv[b][d] (exact flash-style rescale).
// grid = 32 (bag b = blk>>2, d-quarter dq = blk&3), 256 threads.
// ---------------------------------------------------------------------------
__global__ __launch_bounds__(256) void k_combine(
    const float* __restrict__ mpart, const float* __restrict__ spart,
    const float* __restrict__ zpart, float* __restrict__ zv) {
  __shared__ float earr[CPB];
  __shared__ float red[4];
  const int b = blockIdx.x >> 2, dq = blockIdx.x & 3;
  const int t = threadIdx.x, lane = t & 63, w = t >> 6;
  const int base = b * CPB;

  float m = fmaxf(mpart[base + t], mpart[base + 256 + t]);
#pragma unroll
  for (int s = 1; s < 64; s <<= 1) m = fmaxf(m, __shfl_xor(m, s));
  if (lane == 0) red[w] = m;
  __syncthreads();
  m = fmaxf(fmaxf(red[0], red[1]), fmaxf(red[2], red[3]));
  __syncthreads();

  float zpar = 0.f;
  for (int c = t; c < CPB; c += 256) {
    const float e = expf(mpart[base + c] - m);
    earr[c] = e;
    zpar += e * spart[base + c];
  }
#pragma unroll
  for (int s = 1; s < 64; s <<= 1) zpar += __shfl_xor(zpar, s);
  if (lane == 0) red[w] = zpar;
  __syncthreads();
  const float Z = red[0] + red[1] + red[2] + red[3];

  const int d = dq * 256 + t;
  float acc = 0.f;
#pragma unroll 8
  for (int c = 0; c < CPB; ++c)
    acc += earr[c] * zpart[((size_t)(base + c) << 10) + d];
  zv[b * DD + d] = acc / Z;
}

// ---------------------------------------------------------------------------
// Kernel 3: per bag top-64 / bottom-64 ids via 4-pass byte radix select on
// order-preserving uint keys in LDS. Ties -> lowest index (lax.top_k).
// ---------------------------------------------------------------------------
__global__ __launch_bounds__(256) void k_select(
    const float* __restrict__ f, int* __restrict__ sel) {
  __shared__ unsigned int uv[NN];     // swizzled via fvx()
  __shared__ unsigned int hist[256];
  __shared__ unsigned int wq[4];
  __shared__ unsigned int sb[4];      // [0]=pref [1]=above [2]=krem [3]=gcnt
  const int b = blockIdx.x;
  const int t = threadIdx.x;
  const int lane = t & 63, w = t >> 6;
  const float* fb = f + (size_t)b * NN;

  for (int i = t; i < NN; i += 256) uv[fvx(i)] = ordu(fb[i]);
  __syncthreads();

  const int i0 = t * 64;  // contiguous chunk => tie ranks are index-ordered
  for (int mode = 0; mode < 2; ++mode) {
    unsigned int pref = 0u, above = 0u, krem = 64u;
    for (int p = 3; p >= 0; --p) {
      hist[t] = 0u;
      __syncthreads();
      const unsigned int pmask = (p == 3) ? 0u : (0xFFFFFFFFu << ((p + 1) * 8));
      for (int j = 0; j < 64; ++j) {
        unsigned int u = uv[fvx(i0 + j)];
        if (mode) u = ~u;
        if ((u & pmask) == pref)
          atomicAdd(&hist[(u >> (p * 8)) & 255u], 1u);
      }
      __syncthreads();
      const unsigned int v = hist[t];
      unsigned int s = v;
#pragma unroll
      for (int off = 1; off < 64; off <<= 1) {
        const unsigned int o = __shfl_down(s, off);
        if (lane + off < 64) s += o;
      }
      if (lane == 0) wq[w] = s;
      __syncthreads();
      unsigned int hi = 0;
      for (int q = w + 1; q < 4; ++q) hi += wq[q];
      const unsigned int Ssuf = s + hi;
      const unsigned int Snext = Ssuf - v;
      if (Ssuf >= krem && Snext < krem) {
        sb[0] = pref | ((unsigned int)t << (p * 8));
        sb[1] = above + Snext;
        sb[2] = krem - Snext;
        sb[3] = 0u;
      }
      __syncthreads();
      pref = sb[0]; above = sb[1]; krem = sb[2];
    }
    const int off = b * 128 + mode * 64;
    unsigned int myties = 0;
    for (int j = 0; j < 64; ++j) {
      unsigned int u = uv[fvx(i0 + j)];
      if (mode) u = ~u;
      if (u > pref) {
        const unsigned int pos = atomicAdd(&sb[3], 1u);
        sel[off + pos] = i0 + j;
      } else if (u == pref) {
        myties++;
      }
    }
    unsigned int pv = myties;
#pragma unroll
    for (int offp = 1; offp < 64; offp <<= 1) {
      const unsigned int o = __shfl_up(pv, offp);
      if (lane >= offp) pv += o;
    }
    __syncthreads();
    if (lane == 63) wq[w] = pv;
    __syncthreads();
    unsigned int bb = 0;
    for (int q = 0; q < w; ++q) bb += wq[q];
    unsigned int gg = bb + pv - myties;
    for (int j = 0; j < 64 && myties > 0; ++j) {
      unsigned int u = uv[fvx(i0 + j)];
      if (mode) u = ~u;
      if (u == pref) {
        if (gg < krem) sel[off + above + gg] = i0 + j;
        gg++;
        myties--;
      }
    }
    __syncthreads();
  }
}

// ---------------------------------------------------------------------------
// Kernel 4: bag_pred, crit_loss, instance smooth-top1-SVM losses.
// ---------------------------------------------------------------------------
__global__ __launch_bounds__(256) void k_final(
    const float* __restrict__ X, const float* __restrict__ zv,
    const float* __restrict__ Wc, const float* __restrict__ bc,
    const int* __restrict__ labels, const int* __restrict__ sel,
    const float* __restrict__ Wi, const float* __restrict__ bi,
    float* __restrict__ out) {
  const int b = blockIdx.x;
  const int t = threadIdx.x;
  const int lane = t & 63, w = t >> 6;
  __shared__ float sin_[4], sout_[4];
  const int label = labels[b];

  if (w == 0) {
    float s = 0.f;
    const float* zb = zv + b * DD;
#pragma unroll
    for (int j = 0; j < 16; j += 4) {
      const float4 a = *(const float4*)(zb + lane * 16 + j);
      const float4 c = *(const float4*)(Wc + lane * 16 + j);
      s += a.x * c.x + a.y * c.y + a.z * c.z + a.w * c.w;
    }
#pragma unroll
    for (int sh = 1; sh < 64; sh <<= 1) s += __shfl_xor(s, sh);
    if (lane == 0) {
      const float bp = s + bc[0];
      out[b] = bp;
      const float lf = (float)label;
      atomicAdd(out + 8, (softplusf(bp) - bp * lf) * 0.125f);
    }
  }

  const float* Win = Wi + label * (DD * 2);
  const float* Wot = Wi + (1 - label) * (DD * 2);
  const float bin0 = bi[label * 2], bin1 = bi[label * 2 + 1];
  const float bo0 = bi[(1 - label) * 2], bo1 = bi[(1 - label) * 2 + 1];
  float ain = 0.f, aout = 0.f;
  for (int r = w; r < 128; r += 4) {
    const int id = sel[b * 128 + r];
    const float* xr = X + ((size_t)b * NN + id) * DD;
    float p0 = 0.f, p1 = 0.f, p2 = 0.f, p3 = 0.f;
#pragma unroll
    for (int j = 0; j < 16; j += 4) {
      const int d = lane * 16 + j;
      const float4 x = *(const float4*)(xr + d);
      const float4 wa = *(const float4*)(Win + d * 2);
      const float4 wb = *(const float4*)(Win + d * 2 + 4);
      p0 += x.x * wa.x + x.y * wa.z + x.z * wb.x + x.w * wb.z;
      p1 += x.x * wa.y + x.y * wa.w + x.z * wb.y + x.w * wb.w;
      if (r < 64) {
        const float4 oa = *(const float4*)(Wot + d * 2);
        const float4 ob = *(const float4*)(Wot + d * 2 + 4);
        p2 += x.x * oa.x + x.y * oa.z + x.z * ob.x + x.w * ob.z;
        p3 += x.x * oa.y + x.y * oa.w + x.z * ob.y + x.w * ob.w;
      }
    }
#pragma unroll
    for (int sh = 1; sh < 64; sh <<= 1) {
      p0 += __shfl_xor(p0, sh);
      p1 += __shfl_xor(p1, sh);
      p2 += __shfl_xor(p2, sh);
      p3 += __shfl_xor(p3, sh);
    }
    if (lane == 0) {
      const float l0 = p0 + bin0, l1 = p1 + bin1;
      ain += (r < 64) ? softplusf(l0 + 1.f - l1) : softplusf(l1 + 1.f - l0);
      if (r < 64) aout += softplusf((p3 + bo1) + 1.f - (p2 + bo0));
    }
  }
  if (lane == 0) { sin_[w] = ain; sout_[w] = aout; }
  __syncthreads();
  if (t == 0) {
    const float ti = sin_[0] + sin_[1] + sin_[2] + sin_[3];
    const float to = sout_[0] + sout_[1] + sout_[2] + sout_[3];
    atomicAdd(out + 9, ti * (1.0f / 128.0f) + to * (1.0f / 64.0f));
  }
}

// ---------------------------------------------------------------------------

extern "C" void kernel_launch(void* const* d_in, const int* in_sizes, int n_in,
                              void* d_out, int out_size, void* d_ws, size_t ws_size,
                              hipStream_t stream) {
  const float* X      = (const float*)d_in[0];
  const float* mask   = (const float*)d_in[1];
  const int*   labels = (const int*)d_in[2];
  const float* W1     = (const float*)d_in[3];
  const float* b1     = (const float*)d_in[4];
  const float* w2     = (const float*)d_in[5];
  const float* b2     = (const float*)d_in[6];
  const float* Wc     = (const float*)d_in[7];
  const float* bc     = (const float*)d_in[8];
  const float* Wi     = (const float*)d_in[9];
  const float* bi     = (const float*)d_in[10];
  float* out = (float*)d_out;

  float* ws    = (float*)d_ws;
  float* f     = ws;                           // 131072 f32
  float* mpart = ws + 131072;                  // 4096
  float* spart = ws + 135168;                  // 4096
  float* zv    = ws + 139264;                  // 8192
  int*   sel   = (int*)(ws + 147456);          // 1024 int
  unsigned short* W1T = (unsigned short*)(ws + 148480);  // 131072 bf16
  float* zpart = ws + 214016;                  // 4096*1024 f32 = 16 MB

  k_prep   <<<512,  256, 0, stream>>>(W1, W1T, out);
  k_fused  <<<NCH,  512, 0, stream>>>(X, W1T, b1, w2, b2, mask,
                                      f, mpart, spart, zpart);
  k_combine<<<32,   256, 0, stream>>>(mpart, spart, zpart, zv);
  k_select <<<8,    256, 0, stream>>>(f, sel);
  k_final  <<<8,    256, 0, stream>>>(X, zv, Wc, bc, labels, sel, Wi, bi, out);
}

// Round 6
// 383.097 us; speedup vs baseline: 1.2455x; 1.2455x over previous
//
#include <hip/hip_runtime.h>
#include <hip/hip_bf16.h>

#define BB 8
#define NN 16384
#define DD 1024
#define AA 128
#define CHUNK 16                  // rows per fused block
#define NCH (BB * NN / CHUNK)     // 8192 chunks total
#define CPB (NN / CHUNK)          // 1024 chunks per bag

typedef __attribute__((ext_vector_type(8))) short bf16x8;
typedef __attribute__((ext_vector_type(4))) float f32x4;
typedef __attribute__((ext_vector_type(4))) unsigned short u16x4;

__device__ __forceinline__ unsigned short f2bf(float x) {
  union { __hip_bfloat16 h; unsigned short u; } cv;
  cv.h = __float2bfloat16(x);
  return cv.u;
}

__device__ __forceinline__ float bf2f(unsigned short u) {
  return __uint_as_float((unsigned int)u << 16);
}

__device__ __forceinline__ float softplusf(float x) {
  return fmaxf(x, 0.f) + log1pf(expf(-fabsf(x)));
}

// order-preserving float->uint map (monotone)
__device__ __forceinline__ unsigned int ordu(float x) {
  unsigned int u = __float_as_uint(x);
  return (u & 0x80000000u) ? ~u : (u | 0x80000000u);
}

// LDS index swizzle for k_select
__device__ __forceinline__ int fvx(int i) {
  return i ^ ((i >> 6) & 63);
}

// ---------------------------------------------------------------------------
// Kernel 0: W1 -> W1T (bf16, [A=128][D=1024]); zero zv and out[8..9].
// ---------------------------------------------------------------------------
__global__ __launch_bounds__(256) void k_prep(
    const float* __restrict__ W1, unsigned short* __restrict__ W1T,
    float* __restrict__ zv, float* __restrict__ out) {
  const int gid = blockIdx.x * 256 + threadIdx.x;
  if (gid < BB * DD) zv[gid] = 0.f;
  if (gid == 0) { out[8] = 0.f; out[9] = 0.f; }
  if (gid < DD * AA) {
    const int col = gid >> 10;
    const int k   = gid & 1023;
    W1T[gid] = f2bf(W1[k * AA + col]);
  }
}

// ---------------------------------------------------------------------------
// Kernel 1 (fused): per 16-row chunk g (256 threads, 4 waves, ~32.4KB LDS ->
// 4 blocks/CU for phase overlap across independent blocks):
//   - stage X[16][1024] bf16 in LDS (XOR-swizzled)
//   - f rows via MFMA (each wave owns 32 of 128 A-cols; B from L2-resident W1T)
//   - local masked max/sum-exp -> mpart/spart
//   - z partial per thread (d-range of 4, all 16 rows in regs) -> zpart bf16
// ---------------------------------------------------------------------------
__global__ __launch_bounds__(256, 4) void k_fused(
    const float* __restrict__ X, const unsigned short* __restrict__ W1T,
    const float* __restrict__ b1, const float* __restrict__ w2,
    const float* __restrict__ b2p, const float* __restrict__ mask,
    float* __restrict__ f, float* __restrict__ mpart,
    float* __restrict__ spart, unsigned short* __restrict__ zpart) {
  __shared__ unsigned short Xs[CHUNK * 1024];  // 32 KB
  __shared__ float fpart[4][CHUNK];
  __shared__ float wrow[CHUNK];
  const int t = threadIdx.x;
  const int lane = t & 63, wv = t >> 6;
  const int l15 = lane & 15, lg = lane >> 4;
  const int g = blockIdx.x;
  const size_t n0 = (size_t)g * CHUNK;
  const float* Xb = X + n0 * DD;

  // ---- stage: row j, cols t*4..t*4+3 (coalesced 4KB/row) ----
  {
    const int k = t * 4;
    const int kc = (k >> 3);          // 16B chunk index within row
    const int ko = (k & 7);           // element offset within chunk
#pragma unroll
    for (int j = 0; j < CHUNK; ++j) {
      float4 v = *(const float4*)(Xb + (size_t)j * DD + k);
      u16x4 p;
      p.x = f2bf(v.x); p.y = f2bf(v.y); p.z = f2bf(v.z); p.w = f2bf(v.w);
      const int idx = j * 1024 + ((kc ^ (j & 7)) << 3) + ko;
      *(u16x4*)&Xs[idx] = p;
    }
  }
  __syncthreads();

  // ---- MFMA: wave tile 16 rows x 32 cols, K=1024 ----
  f32x4 zero4 = {0.f, 0.f, 0.f, 0.f};
  f32x4 acc0 = zero4, acc1 = zero4;
  const int r = l15;
  const unsigned short* Bp0 = W1T + (size_t)(wv * 32 + l15) * DD;
  const unsigned short* Bp1 = Bp0 + (size_t)16 * DD;
#pragma unroll 8
  for (int ks = 0; ks < 32; ++ks) {
    const int c = ks * 4 + lg;
    const bf16x8 af = *(const bf16x8*)&Xs[r * 1024 + ((c ^ (r & 7)) << 3)];
    const bf16x8 b0 = *(const bf16x8*)(Bp0 + c * 8);
    const bf16x8 b1v = *(const bf16x8*)(Bp1 + c * 8);
    acc0 = __builtin_amdgcn_mfma_f32_16x16x32_bf16(af, b0, acc0, 0, 0, 0);
    acc1 = __builtin_amdgcn_mfma_f32_16x16x32_bf16(af, b1v, acc1, 0, 0, 0);
  }

  // ---- f epilogue: reduce over this wave's 32 cols ----
  const float b2v = b2p[0];
  const float w2a = w2[wv * 32 + l15],      b1a = b1[wv * 32 + l15];
  const float w2b = w2[wv * 32 + 16 + l15], b1b = b1[wv * 32 + 16 + l15];
#pragma unroll
  for (int q = 0; q < 4; ++q) {
    float s = w2a * tanhf(acc0[q] + b1a) + w2b * tanhf(acc1[q] + b1b);
    s += __shfl_xor(s, 1);
    s += __shfl_xor(s, 2);
    s += __shfl_xor(s, 4);
    s += __shfl_xor(s, 8);
    if (l15 == 0) fpart[wv][lg * 4 + q] = s;
  }
  __syncthreads();

  if (t < CHUNK) {
    const float fr = fpart[0][t] + fpart[1][t] + fpart[2][t] + fpart[3][t] + b2v;
    f[n0 + t] = fr;
    const float mk = mask[n0 + t];
    float mb = mk > 0.f ? fr : -1.0e30f;
#pragma unroll
    for (int s = 1; s < 16; s <<= 1) mb = fmaxf(mb, __shfl_xor(mb, s));
    const float w = mk > 0.f ? expf(fr - mb) : 0.f;
    wrow[t] = w;
    float sbv = w;
#pragma unroll
    for (int s = 1; s < 16; s <<= 1) sbv += __shfl_xor(sbv, s);
    if (t == 0) { mpart[g] = mb; spart[g] = sbv; }
  }
  __syncthreads();

  // ---- z partial: thread owns d = t*4..t*4+3, all 16 rows in registers ----
  {
    const int d0 = t * 4;
    const int dc = (d0 >> 3), doff = (d0 & 7);
    float z0 = 0.f, z1 = 0.f, z2 = 0.f, z3 = 0.f;
#pragma unroll
    for (int rr = 0; rr < CHUNK; ++rr) {
      const float w = wrow[rr];
      const u16x4 xv =
          *(const u16x4*)&Xs[rr * 1024 + ((dc ^ (rr & 7)) << 3) + doff];
      z0 += w * bf2f(xv.x);
      z1 += w * bf2f(xv.y);
      z2 += w * bf2f(xv.z);
      z3 += w * bf2f(xv.w);
    }
    u16x4 o;
    o.x = f2bf(z0); o.y = f2bf(z1); o.z = f2bf(z2); o.w = f2bf(z3);
    *(u16x4*)(zpart + (size_t)g * 1024 + d0) = o;
  }
}

// ---------------------------------------------------------------------------
// Kernel 2: per-bag global max M and denom Z from chunk partials. 1 block.
// ---------------------------------------------------------------------------
__global__ __launch_bounds__(256) void k_msum(
    const float* __restrict__ mpart, const float* __restrict__ spart,
    float* __restrict__ msZ) {
  const int t = threadIdx.x, b = t >> 5, li = t & 31;
  float m = -3.0e38f;
  for (int c = li; c < CPB; c += 32) m = fmaxf(m, mpart[b * CPB + c]);
#pragma unroll
  for (int s = 1; s < 32; s <<= 1) m = fmaxf(m, __shfl_xor(m, s));
  float z = 0.f;
  for (int c = li; c < CPB; c += 32)
    z += expf(mpart[b * CPB + c] - m) * spart[b * CPB + c];
#pragma unroll
  for (int s = 1; s < 32; s <<= 1) z += __shfl_xor(z, s);
  if (li == 0) { msZ[b] = m; msZ[8 + b] = z; }
}

// ---------------------------------------------------------------------------
// Kernel 3: combine chunk z-partials -> zv (unnormalized), exact rescale.
// grid = 64 (bag = blk>>3, chunk-group of 128 = blk&7); f32 atomics.
// ---------------------------------------------------------------------------
__global__ __launch_bounds__(256) void k_combine(
    const float* __restrict__ mpart, const unsigned short* __restrict__ zpart,
    const float* __restrict__ msZ, float* __restrict__ zv) {
  __shared__ float earr[128];
  const int b = blockIdx.x >> 3, grp = blockIdx.x & 7;
  const int t = threadIdx.x;
  const int c0 = b * CPB + grp * 128;
  const float M = msZ[b];
  if (t < 128) earr[t] = expf(mpart[c0 + t] - M);
  __syncthreads();
  float a0 = 0.f, a1 = 0.f, a2 = 0.f, a3 = 0.f;
  const int d0 = t * 4;
#pragma unroll 4
  for (int c = 0; c < 128; ++c) {
    const float e = earr[c];
    const u16x4 xv = *(const u16x4*)(zpart + (size_t)(c0 + c) * 1024 + d0);
    a0 += e * bf2f(xv.x);
    a1 += e * bf2f(xv.y);
    a2 += e * bf2f(xv.z);
    a3 += e * bf2f(xv.w);
  }
  float* zb = zv + b * DD + d0;
  atomicAdd(zb + 0, a0);
  atomicAdd(zb + 1, a1);
  atomicAdd(zb + 2, a2);
  atomicAdd(zb + 3, a3);
}

// ---------------------------------------------------------------------------
// Kernel 4: per-bag top/bottom-64 via 4-pass byte radix select, 1024 threads.
// Ties -> lowest index (matches lax.top_k). Wave-parallel scans only.
// ---------------------------------------------------------------------------
__global__ __launch_bounds__(1024) void k_select(
    const float* __restrict__ f, int* __restrict__ sel) {
  __shared__ unsigned int uv[NN];     // 64 KB, swizzled via fvx()
  __shared__ unsigned int hist[256];
  __shared__ unsigned int wq[16];
  __shared__ unsigned int sb[4];      // [0]=pref [1]=above [2]=krem [3]=gcnt
  const int t = threadIdx.x;
  const int lane = t & 63, w = t >> 6;
  const int b = blockIdx.x;
  const float* fb = f + (size_t)b * NN;

  for (int i = t; i < NN; i += 1024) uv[fvx(i)] = ordu(fb[i]);
  __syncthreads();

  const int i0 = t * 16;  // contiguous chunk => tie ranks index-ordered
  for (int mode = 0; mode < 2; ++mode) {
    unsigned int pref = 0u, above = 0u, krem = 64u;
    for (int p = 3; p >= 0; --p) {
      if (t < 256) hist[t] = 0u;
      __syncthreads();
      const unsigned int pmask = (p == 3) ? 0u : (0xFFFFFFFFu << ((p + 1) * 8));
      for (int j = 0; j < 16; ++j) {
        unsigned int u = uv[fvx(i0 + j)];
        if (mode) u = ~u;
        if ((u & pmask) == pref)
          atomicAdd(&hist[(u >> (p * 8)) & 255u], 1u);
      }
      __syncthreads();
      unsigned int v = 0, s = 0;
      if (t < 256) {
        v = hist[t];
        s = v;
#pragma unroll
        for (int off = 1; off < 64; off <<= 1) {
          const unsigned int o = __shfl_down(s, off);
          if (lane + off < 64) s += o;
        }
        if (lane == 0) wq[w] = s;
      }
      __syncthreads();
      if (t < 256) {
        unsigned int hi = 0;
        for (int q = w + 1; q < 4; ++q) hi += wq[q];
        const unsigned int Ssuf = s + hi;
        const unsigned int Snext = Ssuf - v;
        if (Ssuf >= krem && Snext < krem) {
          sb[0] = pref | ((unsigned int)t << (p * 8));
          sb[1] = above + Snext;
          sb[2] = krem - Snext;
          sb[3] = 0u;
        }
      }
      __syncthreads();
      pref = sb[0]; above = sb[1]; krem = sb[2];
    }
    const int off = b * 128 + mode * 64;
    unsigned int myt = 0;
    for (int j = 0; j < 16; ++j) {
      unsigned int u = uv[fvx(i0 + j)];
      if (mode) u = ~u;
      if (u > pref) {
        const unsigned int pos = atomicAdd(&sb[3], 1u);
        sel[off + pos] = i0 + j;
      } else if (u == pref) {
        myt++;
      }
    }
    unsigned int pv = myt;
#pragma unroll
    for (int o2 = 1; o2 < 64; o2 <<= 1) {
      const unsigned int o = __shfl_up(pv, o2);
      if (lane >= o2) pv += o;
    }
    __syncthreads();
    if (lane == 63) wq[w] = pv;
    __syncthreads();
    unsigned int base = 0;
    for (int q = 0; q < w; ++q) base += wq[q];
    unsigned int gg = base + pv - myt;
    for (int j = 0; j < 16 && myt > 0; ++j) {
      unsigned int u = uv[fvx(i0 + j)];
      if (mode) u = ~u;
      if (u == pref) {
        if (gg < krem) sel[off + above + gg] = i0 + j;
        gg++;
        myt--;
      }
    }
    __syncthreads();
  }
}

// ---------------------------------------------------------------------------
// Kernel 5: bag_pred (zv/Z), crit_loss, instance smooth-top1-SVM losses.
// grid = 32 (bag = blk>>2, row-quarter = blk&3).
// ---------------------------------------------------------------------------
__global__ __launch_bounds__(256) void k_final(
    const float* __restrict__ X, const float* __restrict__ zv,
    const float* __restrict__ msZ, const float* __restrict__ Wc,
    const float* __restrict__ bc, const int* __restrict__ labels,
    const int* __restrict__ sel, const float* __restrict__ Wi,
    const float* __restrict__ bi, float* __restrict__ out) {
  const int b = blockIdx.x >> 2, part = blockIdx.x & 3;
  const int t = threadIdx.x;
  const int lane = t & 63, w = t >> 6;
  __shared__ float sin_[4], sout_[4];
  const int label = labels[b];

  if (part == 0 && w == 0) {
    float s = 0.f;
    const float* zb = zv + b * DD;
#pragma unroll
    for (int j = 0; j < 16; j += 4) {
      const float4 a = *(const float4*)(zb + lane * 16 + j);
      const float4 c = *(const float4*)(Wc + lane * 16 + j);
      s += a.x * c.x + a.y * c.y + a.z * c.z + a.w * c.w;
    }
#pragma unroll
    for (int sh = 1; sh < 64; sh <<= 1) s += __shfl_xor(s, sh);
    if (lane == 0) {
      const float bp = s / msZ[8 + b] + bc[0];
      out[b] = bp;
      const float lf = (float)label;
      atomicAdd(out + 8, (softplusf(bp) - bp * lf) * 0.125f);
    }
  }

  const float* Win = Wi + label * (DD * 2);
  const float* Wot = Wi + (1 - label) * (DD * 2);
  const float bin0 = bi[label * 2], bin1 = bi[label * 2 + 1];
  const float bo0 = bi[(1 - label) * 2], bo1 = bi[(1 - label) * 2 + 1];
  float ain = 0.f, aout = 0.f;
  for (int ii = 0; ii < 8; ++ii) {
    const int r = part * 32 + w * 8 + ii;     // 0..127
    const int id = sel[b * 128 + r];
    const float* xr = X + ((size_t)b * NN + id) * DD;
    float p0 = 0.f, p1 = 0.f, p2 = 0.f, p3 = 0.f;
#pragma unroll
    for (int j = 0; j < 16; j += 4) {
      const int d = lane * 16 + j;
      const float4 x = *(const float4*)(xr + d);
      const float4 wa = *(const float4*)(Win + d * 2);
      const float4 wb = *(const float4*)(Win + d * 2 + 4);
      p0 += x.x * wa.x + x.y * wa.z + x.z * wb.x + x.w * wb.z;
      p1 += x.x * wa.y + x.y * wa.w + x.z * wb.y + x.w * wb.w;
      if (r < 64) {
        const float4 oa = *(const float4*)(Wot + d * 2);
        const float4 ob = *(const float4*)(Wot + d * 2 + 4);
        p2 += x.x * oa.x + x.y * oa.z + x.z * ob.x + x.w * ob.z;
        p3 += x.x * oa.y + x.y * oa.w + x.z * ob.y + x.w * ob.w;
      }
    }
#pragma unroll
    for (int sh = 1; sh < 64; sh <<= 1) {
      p0 += __shfl_xor(p0, sh);
      p1 += __shfl_xor(p1, sh);
      p2 += __shfl_xor(p2, sh);
      p3 += __shfl_xor(p3, sh);
    }
    if (lane == 0) {
      const float l0 = p0 + bin0, l1 = p1 + bin1;
      ain += (r < 64) ? softplusf(l0 + 1.f - l1) : softplusf(l1 + 1.f - l0);
      if (r < 64) aout += softplusf((p3 + bo1) + 1.f - (p2 + bo0));
    }
  }
  if (lane == 0) { sin_[w] = ain; sout_[w] = aout; }
  __syncthreads();
  if (t == 0) {
    const float ti = sin_[0] + sin_[1] + sin_[2] + sin_[3];
    const float to = sout_[0] + sout_[1] + sout_[2] + sout_[3];
    atomicAdd(out + 9, ti * (1.0f / 128.0f) + to * (1.0f / 64.0f));
  }
}

// ---------------------------------------------------------------------------

extern "C" void kernel_launch(void* const* d_in, const int* in_sizes, int n_in,
                              void* d_out, int out_size, void* d_ws, size_t ws_size,
                              hipStream_t stream) {
  const float* X      = (const float*)d_in[0];
  const float* mask   = (const float*)d_in[1];
  const int*   labels = (const int*)d_in[2];
  const float* W1     = (const float*)d_in[3];
  const float* b1     = (const float*)d_in[4];
  const float* w2     = (const float*)d_in[5];
  const float* b2     = (const float*)d_in[6];
  const float* Wc     = (const float*)d_in[7];
  const float* bc     = (const float*)d_in[8];
  const float* Wi     = (const float*)d_in[9];
  const float* bi     = (const float*)d_in[10];
  float* out = (float*)d_out;

  float* ws    = (float*)d_ws;
  float* f     = ws;                           // 131072 f32
  float* mpart = ws + 131072;                  // 8192
  float* spart = ws + 139264;                  // 8192
  float* msZ   = ws + 147456;                  // 16 (M[8], Z[8])
  float* zv    = ws + 147472;                  // 8192
  int*   sel   = (int*)(ws + 155664);          // 1024 int
  unsigned short* W1T   = (unsigned short*)(ws + 156688);  // 131072 bf16
  unsigned short* zpart = (unsigned short*)(ws + 222224);  // 8192*1024 bf16 = 16 MB

  k_prep   <<<512,  256, 0, stream>>>(W1, W1T, zv, out);
  k_fused  <<<NCH,  256, 0, stream>>>(X, W1T, b1, w2, b2, mask,
                                      f, mpart, spart, zpart);
  k_msum   <<<1,    256, 0, stream>>>(mpart, spart, msZ);
  k_combine<<<64,   256, 0, stream>>>(mpart, zpart, msZ, zv);
  k_select <<<8,   1024, 0, stream>>>(f, sel);
  k_final  <<<32,   256, 0, stream>>>(X, zv, msZ, Wc, bc, labels, sel, Wi, bi, out);
}

// Round 7
// 338.375 us; speedup vs baseline: 1.4101x; 1.1322x over previous
//
#include <hip/hip_runtime.h>
#include <hip/hip_bf16.h>

#define BB 8
#define NN 16384
#define DD 1024
#define AA 128
#define CHUNK 16                  // rows per chunk
#define CHPB 8                    // chunks per block
#define ROWS_PB (CHUNK * CHPB)    // 128 rows per block
#define NBLK (BB * NN / ROWS_PB)  // 1024 blocks
#define CPB (NN / ROWS_PB)        // 128 blocks per bag

typedef __attribute__((ext_vector_type(8))) short bf16x8;
typedef __attribute__((ext_vector_type(4))) float f32x4;
typedef __attribute__((ext_vector_type(4))) unsigned short u16x4;

__device__ __forceinline__ unsigned short f2bf(float x) {
  union { __hip_bfloat16 h; unsigned short u; } cv;
  cv.h = __float2bfloat16(x);
  return cv.u;
}

__device__ __forceinline__ float bf2f(unsigned short u) {
  return __uint_as_float((unsigned int)u << 16);
}

__device__ __forceinline__ float softplusf(float x) {
  return fmaxf(x, 0.f) + log1pf(expf(-fabsf(x)));
}

// order-preserving float->uint map (monotone)
__device__ __forceinline__ unsigned int ordu(float x) {
  unsigned int u = __float_as_uint(x);
  return (u & 0x80000000u) ? ~u : (u | 0x80000000u);
}

// LDS index swizzle for k_select
__device__ __forceinline__ int fvx(int i) {
  return i ^ ((i >> 6) & 63);
}

// ---------------------------------------------------------------------------
// Kernel 0: W1 -> W1T (bf16, [A=128][D=1024]); zero out[8..9].
// ---------------------------------------------------------------------------
__global__ __launch_bounds__(256) void k_prep(
    const float* __restrict__ W1, unsigned short* __restrict__ W1T,
    float* __restrict__ out) {
  const int gid = blockIdx.x * 256 + threadIdx.x;
  if (gid == 0) { out[8] = 0.f; out[9] = 0.f; }
  if (gid < DD * AA) {
    const int col = gid >> 10;
    const int k   = gid & 1023;
    W1T[gid] = f2bf(W1[k * AA + col]);
  }
}

// ---------------------------------------------------------------------------
// Kernel 1 (fused v2): 512 threads / 8 waves; each wave owns 16 of 128 A-cols
// with its FULL B-panel (32 MFMA fragments = 128 VGPR) preloaded to registers.
// Block processes 8 chunks x 16 rows (128 rows), LDS double-buffered:
//   issue loads(c+1) -> MFMA(c) from LDS (no global in loop) -> f epilogue
//   -> online-softmax z accumulation in regs -> cvt+write staged (c+1) -> bar.
// Outputs: f, per-block (m, s, z[1024]) flash partials.
// ---------------------------------------------------------------------------
__global__ __launch_bounds__(512, 2) void k_fused(
    const float* __restrict__ X, const unsigned short* __restrict__ W1T,
    const float* __restrict__ b1, const float* __restrict__ w2,
    const float* __restrict__ b2p, const float* __restrict__ mask,
    float* __restrict__ f, float* __restrict__ mpart,
    float* __restrict__ spart, float* __restrict__ zpart) {
  __shared__ unsigned short Xs[2][CHUNK * 1024];   // 2 x 32 KB
  __shared__ float fpart[8][CHUNK];
  __shared__ float wrow[CHUNK];
  __shared__ float mrow[ROWS_PB];
  __shared__ float bc2[2];
  const int t = threadIdx.x;
  const int lane = t & 63, wv = t >> 6;
  const int l15 = lane & 15, lg = lane >> 4;
  const int g = blockIdx.x;
  const size_t n0 = (size_t)g * ROWS_PB;

  // ---- preload B panel: wave's 16 cols x K=1024 -> 32 fragments in regs ----
  bf16x8 breg[32];
  {
    const unsigned short* Bp = W1T + (size_t)(wv * 16 + l15) * 1024 + lg * 8;
#pragma unroll
    for (int kk = 0; kk < 32; ++kk)
      breg[kk] = *(const bf16x8*)(Bp + kk * 32);
  }
  const float w2c = w2[wv * 16 + l15];
  const float b1c = b1[wv * 16 + l15];
  const float b2v = b2p[0];
  if (t < ROWS_PB) mrow[t] = mask[n0 + t];

  const int row_t = t >> 8;          // 0..1
  const int col = (t & 255) * 4;     // 0..1020
  const int kc = col >> 3, ko = col & 7;

  float4 st[8];
  // ---- prologue: stage chunk 0 ----
  {
    const float* Xc = X + n0 * DD;
#pragma unroll
    for (int s = 0; s < 8; ++s)
      st[s] = *(const float4*)(Xc + (size_t)(s * 2 + row_t) * DD + col);
#pragma unroll
    for (int s = 0; s < 8; ++s) {
      const int j = s * 2 + row_t;
      u16x4 p;
      p.x = f2bf(st[s].x); p.y = f2bf(st[s].y);
      p.z = f2bf(st[s].z); p.w = f2bf(st[s].w);
      *(u16x4*)&Xs[0][j * 1024 + ((kc ^ (j & 7)) << 3) + ko] = p;
    }
  }
  __syncthreads();

  float z0 = 0.f, z1 = 0.f, m_run = -3.0e38f, s_run = 0.f;
  const int d0 = t * 2;
  const int dc = d0 >> 3, doff = d0 & 7;
  int cur = 0;

  for (int ch = 0; ch < CHPB; ++ch) {
    // issue next chunk's loads early (land under compute below)
    if (ch < CHPB - 1) {
      const float* Xc = X + (n0 + (size_t)(ch + 1) * CHUNK) * DD;
#pragma unroll
      for (int s = 0; s < 8; ++s)
        st[s] = *(const float4*)(Xc + (size_t)(s * 2 + row_t) * DD + col);
    }

    // ---- MFMA: 16 rows x 16 cols per wave, K=1024, LDS + regs only ----
    f32x4 acc = {0.f, 0.f, 0.f, 0.f};
    {
      const unsigned short* Xr = &Xs[cur][l15 * 1024];
      const int rx = l15 & 7;
#pragma unroll
      for (int kk = 0; kk < 32; ++kk) {
        const bf16x8 af = *(const bf16x8*)&Xr[((kk * 4 + lg) ^ rx) << 3];
        acc = __builtin_amdgcn_mfma_f32_16x16x32_bf16(af, breg[kk], acc, 0, 0, 0);
      }
    }
#pragma unroll
    for (int q = 0; q < 4; ++q) {
      float s = w2c * tanhf(acc[q] + b1c);
      s += __shfl_xor(s, 1);
      s += __shfl_xor(s, 2);
      s += __shfl_xor(s, 4);
      s += __shfl_xor(s, 8);
      if (l15 == 0) fpart[wv][lg * 4 + q] = s;
    }
    __syncthreads();                      // B1: fpart ready

    if (t < CHUNK) {
      const float fr = fpart[0][t] + fpart[1][t] + fpart[2][t] + fpart[3][t] +
                       fpart[4][t] + fpart[5][t] + fpart[6][t] + fpart[7][t] + b2v;
      f[n0 + ch * CHUNK + t] = fr;
      const float mk = mrow[ch * CHUNK + t];
      float fv = mk > 0.f ? fr : -1.0e30f;
      float mc = fv;
#pragma unroll
      for (int s = 1; s < 16; s <<= 1) mc = fmaxf(mc, __shfl_xor(mc, s));
      const float m_new = fmaxf(m_run, mc);
      const float w = mk > 0.f ? expf(fr - m_new) : 0.f;
      wrow[t] = w;
      float sc = w;
#pragma unroll
      for (int s = 1; s < 16; s <<= 1) sc += __shfl_xor(sc, s);
      if (t == 0) { bc2[0] = mc; bc2[1] = sc; }
    }
    __syncthreads();                      // B2: wrow/bc2 ready

    {
      const float mc = bc2[0], sc = bc2[1];
      const float m_new = fmaxf(m_run, mc);
      const float resc = expf(m_run - m_new);
      m_run = m_new;
      s_run = s_run * resc + sc;
      z0 *= resc; z1 *= resc;
#pragma unroll
      for (int rr = 0; rr < CHUNK; ++rr) {
        const float w = wrow[rr];
        const unsigned int xv = *(const unsigned int*)
            &Xs[cur][rr * 1024 + ((dc ^ (rr & 7)) << 3) + doff];
        z0 += w * bf2f((unsigned short)(xv & 0xFFFFu));
        z1 += w * bf2f((unsigned short)(xv >> 16));
      }
    }

    // write staged chunk c+1 to the other buffer (waits on loads here)
    if (ch < CHPB - 1) {
#pragma unroll
      for (int s = 0; s < 8; ++s) {
        const int j = s * 2 + row_t;
        u16x4 p;
        p.x = f2bf(st[s].x); p.y = f2bf(st[s].y);
        p.z = f2bf(st[s].z); p.w = f2bf(st[s].w);
        *(u16x4*)&Xs[cur ^ 1][j * 1024 + ((kc ^ (j & 7)) << 3) + ko] = p;
      }
    }
    __syncthreads();                      // B3: next buffer ready
    cur ^= 1;
  }

  zpart[(size_t)g * 1024 + d0] = z0;
  zpart[(size_t)g * 1024 + d0 + 1] = z1;
  if (t == 0) { mpart[g] = m_run; spart[g] = s_run; }
}

// ---------------------------------------------------------------------------
// Kernel 2: per-bag global max M and denom Z from block partials. 1 block.
// ---------------------------------------------------------------------------
__global__ __launch_bounds__(256) void k_msum(
    const float* __restrict__ mpart, const float* __restrict__ spart,
    float* __restrict__ msZ) {
  const int t = threadIdx.x, b = t >> 5, li = t & 31;
  float m = -3.0e38f;
  for (int c = li; c < CPB; c += 32) m = fmaxf(m, mpart[b * CPB + c]);
#pragma unroll
  for (int s = 1; s < 32; s <<= 1) m = fmaxf(m, __shfl_xor(m, s));
  float z = 0.f;
  for (int c = li; c < CPB; c += 32)
    z += expf(mpart[b * CPB + c] - m) * spart[b * CPB + c];
#pragma unroll
  for (int s = 1; s < 32; s <<= 1) z += __shfl_xor(z, s);
  if (li == 0) { msZ[b] = m; msZ[8 + b] = z; }
}

// ---------------------------------------------------------------------------
// Kernel 3: combine block z-partials -> normalized zv[b][d] (exact rescale).
// grid = 32 (bag = blk>>2, d-quarter = blk&3); no atomics.
// ---------------------------------------------------------------------------
__global__ __launch_bounds__(256) void k_combine(
    const float* __restrict__ mpart, const float* __restrict__ zpart,
    const float* __restrict__ msZ, float* __restrict__ zv) {
  __shared__ float earr[CPB];
  const int b = blockIdx.x >> 2, dq = blockIdx.x & 3;
  const int t = threadIdx.x;
  const float M = msZ[b];
  if (t < CPB) earr[t] = expf(mpart[b * CPB + t] - M);
  __syncthreads();
  const int d = dq * 256 + t;
  float acc = 0.f;
#pragma unroll 4
  for (int c = 0; c < CPB; ++c)
    acc += earr[c] * zpart[(size_t)(b * CPB + c) * 1024 + d];
  zv[b * DD + d] = acc / msZ[8 + b];
}

// ---------------------------------------------------------------------------
// Kernel 4: per-bag top/bottom-64 via 4-pass byte radix select, 1024 threads.
// Ties -> lowest index (matches lax.top_k). Wave-parallel scans only.
// ---------------------------------------------------------------------------
__global__ __launch_bounds__(1024) void k_select(
    const float* __restrict__ f, int* __restrict__ sel) {
  __shared__ unsigned int uv[NN];     // 64 KB, swizzled via fvx()
  __shared__ unsigned int hist[256];
  __shared__ unsigned int wq[16];
  __shared__ unsigned int sb[4];      // [0]=pref [1]=above [2]=krem [3]=gcnt
  const int t = threadIdx.x;
  const int lane = t & 63, w = t >> 6;
  const int b = blockIdx.x;
  const float* fb = f + (size_t)b * NN;

  for (int i = t; i < NN; i += 1024) uv[fvx(i)] = ordu(fb[i]);
  __syncthreads();

  const int i0 = t * 16;  // contiguous chunk => tie ranks index-ordered
  for (int mode = 0; mode < 2; ++mode) {
    unsigned int pref = 0u, above = 0u, krem = 64u;
    for (int p = 3; p >= 0; --p) {
      if (t < 256) hist[t] = 0u;
      __syncthreads();
      const unsigned int pmask = (p == 3) ? 0u : (0xFFFFFFFFu << ((p + 1) * 8));
      for (int j = 0; j < 16; ++j) {
        unsigned int u = uv[fvx(i0 + j)];
        if (mode) u = ~u;
        if ((u & pmask) == pref)
          atomicAdd(&hist[(u >> (p * 8)) & 255u], 1u);
      }
      __syncthreads();
      unsigned int v = 0, s = 0;
      if (t < 256) {
        v = hist[t];
        s = v;
#pragma unroll
        for (int off = 1; off < 64; off <<= 1) {
          const unsigned int o = __shfl_down(s, off);
          if (lane + off < 64) s += o;
        }
        if (lane == 0) wq[w] = s;
      }
      __syncthreads();
      if (t < 256) {
        unsigned int hi = 0;
        for (int q = w + 1; q < 4; ++q) hi += wq[q];
        const unsigned int Ssuf = s + hi;
        const unsigned int Snext = Ssuf - v;
        if (Ssuf >= krem && Snext < krem) {
          sb[0] = pref | ((unsigned int)t << (p * 8));
          sb[1] = above + Snext;
          sb[2] = krem - Snext;
          sb[3] = 0u;
        }
      }
      __syncthreads();
      pref = sb[0]; above = sb[1]; krem = sb[2];
    }
    const int off = b * 128 + mode * 64;
    unsigned int myt = 0;
    for (int j = 0; j < 16; ++j) {
      unsigned int u = uv[fvx(i0 + j)];
      if (mode) u = ~u;
      if (u > pref) {
        const unsigned int pos = atomicAdd(&sb[3], 1u);
        sel[off + pos] = i0 + j;
      } else if (u == pref) {
        myt++;
      }
    }
    unsigned int pv = myt;
#pragma unroll
    for (int o2 = 1; o2 < 64; o2 <<= 1) {
      const unsigned int o = __shfl_up(pv, o2);
      if (lane >= o2) pv += o;
    }
    __syncthreads();
    if (lane == 63) wq[w] = pv;
    __syncthreads();
    unsigned int base = 0;
    for (int q = 0; q < w; ++q) base += wq[q];
    unsigned int gg = base + pv - myt;
    for (int j = 0; j < 16 && myt > 0; ++j) {
      unsigned int u = uv[fvx(i0 + j)];
      if (mode) u = ~u;
      if (u == pref) {
        if (gg < krem) sel[off + above + gg] = i0 + j;
        gg++;
        myt--;
      }
    }
    __syncthreads();
  }
}

// ---------------------------------------------------------------------------
// Kernel 5: bag_pred (zv normalized), crit_loss, instance SVM losses.
// grid = 32 (bag = blk>>2, row-quarter = blk&3).
// ---------------------------------------------------------------------------
__global__ __launch_bounds__(256) void k_final(
    const float* __restrict__ X, const float* __restrict__ zv,
    const float* __restrict__ Wc, const float* __restrict__ bc,
    const int* __restrict__ labels, const int* __restrict__ sel,
    const float* __restrict__ Wi, const float* __restrict__ bi,
    float* __restrict__ out) {
  const int b = blockIdx.x >> 2, part = blockIdx.x & 3;
  const int t = threadIdx.x;
  const int lane = t & 63, w = t >> 6;
  __shared__ float sin_[4], sout_[4];
  const int label = labels[b];

  if (part == 0 && w == 0) {
    float s = 0.f;
    const float* zb = zv + b * DD;
#pragma unroll
    for (int j = 0; j < 16; j += 4) {
      const float4 a = *(const float4*)(zb + lane * 16 + j);
      const float4 c = *(const float4*)(Wc + lane * 16 + j);
      s += a.x * c.x + a.y * c.y + a.z * c.z + a.w * c.w;
    }
#pragma unroll
    for (int sh = 1; sh < 64; sh <<= 1) s += __shfl_xor(s, sh);
    if (lane == 0) {
      const float bp = s + bc[0];
      out[b] = bp;
      const float lf = (float)label;
      atomicAdd(out + 8, (softplusf(bp) - bp * lf) * 0.125f);
    }
  }

  const float* Win = Wi + label * (DD * 2);
  const float* Wot = Wi + (1 - label) * (DD * 2);
  const float bin0 = bi[label * 2], bin1 = bi[label * 2 + 1];
  const float bo0 = bi[(1 - label) * 2], bo1 = bi[(1 - label) * 2 + 1];
  float ain = 0.f, aout = 0.f;
  for (int ii = 0; ii < 8; ++ii) {
    const int r = part * 32 + w * 8 + ii;     // 0..127
    const int id = sel[b * 128 + r];
    const float* xr = X + ((size_t)b * NN + id) * DD;
    float p0 = 0.f, p1 = 0.f, p2 = 0.f, p3 = 0.f;
#pragma unroll
    for (int j = 0; j < 16; j += 4) {
      const int d = lane * 16 + j;
      const float4 x = *(const float4*)(xr + d);
      const float4 wa = *(const float4*)(Win + d * 2);
      const float4 wb = *(const float4*)(Win + d * 2 + 4);
      p0 += x.x * wa.x + x.y * wa.z + x.z * wb.x + x.w * wb.z;
      p1 += x.x * wa.y + x.y * wa.w + x.z * wb.y + x.w * wb.w;
      if (r < 64) {
        const float4 oa = *(const float4*)(Wot + d * 2);
        const float4 ob = *(const float4*)(Wot + d * 2 + 4);
        p2 += x.x * oa.x + x.y * oa.z + x.z * ob.x + x.w * ob.z;
        p3 += x.x * oa.y + x.y * oa.w + x.z * ob.y + x.w * ob.w;
      }
    }
#pragma unroll
    for (int sh = 1; sh < 64; sh <<= 1) {
      p0 += __shfl_xor(p0, sh);
      p1 += __shfl_xor(p1, sh);
      p2 += __shfl_xor(p2, sh);
      p3 += __shfl_xor(p3, sh);
    }
    if (lane == 0) {
      const float l0 = p0 + bin0, l1 = p1 + bin1;
      ain += (r < 64) ? softplusf(l0 + 1.f - l1) : softplusf(l1 + 1.f - l0);
      if (r < 64) aout += softplusf((p3 + bo1) + 1.f - (p2 + bo0));
    }
  }
  if (lane == 0) { sin_[w] = ain; sout_[w] = aout; }
  __syncthreads();
  if (t == 0) {
    const float ti = sin_[0] + sin_[1] + sin_[2] + sin_[3];
    const float to = sout_[0] + sout_[1] + sout_[2] + sout_[3];
    atomicAdd(out + 9, ti * (1.0f / 128.0f) + to * (1.0f / 64.0f));
  }
}

// ---------------------------------------------------------------------------

extern "C" void kernel_launch(void* const* d_in, const int* in_sizes, int n_in,
                              void* d_out, int out_size, void* d_ws, size_t ws_size,
                              hipStream_t stream) {
  const float* X      = (const float*)d_in[0];
  const float* mask   = (const float*)d_in[1];
  const int*   labels = (const int*)d_in[2];
  const float* W1     = (const float*)d_in[3];
  const float* b1     = (const float*)d_in[4];
  const float* w2     = (const float*)d_in[5];
  const float* b2     = (const float*)d_in[6];
  const float* Wc     = (const float*)d_in[7];
  const float* bc     = (const float*)d_in[8];
  const float* Wi     = (const float*)d_in[9];
  const float* bi     = (const float*)d_in[10];
  float* out = (float*)d_out;

  float* ws    = (float*)d_ws;
  float* f     = ws;                           // 131072 f32
  float* mpart = ws + 131072;                  // 1024
  float* spart = ws + 132096;                  // 1024
  float* msZ   = ws + 133120;                  // 16 (M[8], Z[8])
  float* zv    = ws + 133136;                  // 8192
  int*   sel   = (int*)(ws + 141328);          // 1024 int
  unsigned short* W1T = (unsigned short*)(ws + 142352);  // 131072 bf16
  float* zpart = ws + 207888;                  // 1024*1024 f32 = 4 MB

  k_prep   <<<512,  256, 0, stream>>>(W1, W1T, out);
  k_fused  <<<NBLK, 512, 0, stream>>>(X, W1T, b1, w2, b2, mask,
                                      f, mpart, spart, zpart);
  k_msum   <<<1,    256, 0, stream>>>(mpart, spart, msZ);
  k_combine<<<32,   256, 0, stream>>>(mpart, zpart, msZ, zv);
  k_select <<<8,   1024, 0, stream>>>(f, sel);
  k_final  <<<32,   256, 0, stream>>>(X, zv, Wc, bc, labels, sel, Wi, bi, out);
}

// Round 8
// 219.326 us; speedup vs baseline: 2.1755x; 1.5428x over previous
//
#include <hip/hip_runtime.h>
#include <hip/hip_bf16.h>

#define BB 8
#define NN 16384
#define DD 1024
#define AA 128

typedef __attribute__((ext_vector_type(8))) short bf16x8;
typedef __attribute__((ext_vector_type(4))) float f32x4;
typedef __attribute__((ext_vector_type(4))) unsigned short u16x4;

__device__ __forceinline__ unsigned short f2bf(float x) {
  union { __hip_bfloat16 h; unsigned short u; } cv;
  cv.h = __float2bfloat16(x);
  return cv.u;
}

__device__ __forceinline__ float softplusf(float x) {
  return fmaxf(x, 0.f) + log1pf(expf(-fabsf(x)));
}

// order-preserving float->uint map (monotone)
__device__ __forceinline__ unsigned int ordu(float x) {
  unsigned int u = __float_as_uint(x);
  return (u & 0x80000000u) ? ~u : (u | 0x80000000u);
}

// LDS index swizzle for k_select
__device__ __forceinline__ int fvx(int i) {
  return i ^ ((i >> 6) & 63);
}

// ---------------------------------------------------------------------------
// Kernel 0: W1 -> W1T (bf16, [A=128][D=1024]); zero out[8..9].
// ---------------------------------------------------------------------------
__global__ __launch_bounds__(256) void k_prep(
    const float* __restrict__ W1, unsigned short* __restrict__ W1T,
    float* __restrict__ out) {
  const int gid = blockIdx.x * 256 + threadIdx.x;
  if (gid == 0) { out[8] = 0.f; out[9] = 0.f; }
  if (gid < DD * AA) {
    const int col = gid >> 10;
    const int k   = gid & 1023;
    W1T[gid] = f2bf(W1[k * AA + col]);
  }
}

// ---------------------------------------------------------------------------
// Kernel 1: f[n] = b2 + sum_a w2[a] tanh((X W1)[n][a] + b1[a]);
//           y[n] = X[n,:] . Wc  (computed from the SAME staged registers).
// R1-proven structure: 1024 blocks x 256 thr (4 waves 2x2), tile 128x128,
// 16 K-steps of 64, XOR-swizzled LDS, single X read.
// ---------------------------------------------------------------------------
__global__ __launch_bounds__(256) void k_scores(
    const float* __restrict__ X, const unsigned short* __restrict__ W1T,
    const float* __restrict__ b1, const float* __restrict__ w2,
    const float* __restrict__ b2p, const float* __restrict__ Wc,
    float* __restrict__ f, float* __restrict__ y) {
  __shared__ unsigned short As[128 * 64];   // [row][k] bf16, swizzled
  __shared__ unsigned short Bs[128 * 64];   // [col][k] bf16, swizzled
  __shared__ float fpart[128];
  const int t = threadIdx.x;
  const int lane = t & 63;
  const int wv = t >> 6;
  const int wr = wv >> 1, wc = wv & 1;
  const int l15 = lane & 15, lg = lane >> 4;
  const size_t row0 = (size_t)blockIdx.x * 128;
  const float* Xb = X + row0 * DD;

  f32x4 zero4 = {0.f, 0.f, 0.f, 0.f};
  f32x4 acc[4][4];
#pragma unroll
  for (int mi = 0; mi < 4; ++mi)
#pragma unroll
    for (int ni = 0; ni < 4; ++ni) acc[mi][ni] = zero4;

  float yp[8];
#pragma unroll
  for (int j = 0; j < 8; ++j) yp[j] = 0.f;

  for (int st = 0; st < 16; ++st) {
    const int k0 = st * 64;
    const int kq = (t & 15) * 4;              // same k-offset for all j
    const float4 wc4 = *(const float4*)(Wc + k0 + kq);
#pragma unroll
    for (int j = 0; j < 8; ++j) {
      const int i = t + j * 256;
      const int r = i >> 4;
      float4 v = *(const float4*)(Xb + (size_t)r * DD + k0 + kq);
      yp[j] += v.x * wc4.x + v.y * wc4.y + v.z * wc4.z + v.w * wc4.w;
      u16x4 p;
      p.x = f2bf(v.x); p.y = f2bf(v.y); p.z = f2bf(v.z); p.w = f2bf(v.w);
      const int idx = r * 64 + (((kq >> 3) ^ (r & 7)) << 3) + (kq & 7);
      *(u16x4*)&As[idx] = p;
    }
#pragma unroll
    for (int j = 0; j < 4; ++j) {
      const int i = t + j * 256;
      const int col = i >> 3, ch = i & 7;
      bf16x8 vv = *(const bf16x8*)(W1T + (size_t)col * DD + k0 + ch * 8);
      *(bf16x8*)&Bs[col * 64 + ((ch ^ (col & 7)) << 3)] = vv;
    }
    __syncthreads();
#pragma unroll
    for (int ks = 0; ks < 2; ++ks) {
      bf16x8 af[4], bg[4];
      const int chunk = ks * 4 + lg;
#pragma unroll
      for (int mi = 0; mi < 4; ++mi) {
        const int r = wr * 64 + mi * 16 + l15;
        af[mi] = *(const bf16x8*)&As[r * 64 + ((chunk ^ (r & 7)) << 3)];
      }
#pragma unroll
      for (int ni = 0; ni < 4; ++ni) {
        const int c = wc * 64 + ni * 16 + l15;
        bg[ni] = *(const bf16x8*)&Bs[c * 64 + ((chunk ^ (c & 7)) << 3)];
      }
#pragma unroll
      for (int mi = 0; mi < 4; ++mi)
#pragma unroll
        for (int ni = 0; ni < 4; ++ni)
          acc[mi][ni] = __builtin_amdgcn_mfma_f32_16x16x32_bf16(
              af[mi], bg[ni], acc[mi][ni], 0, 0, 0);
    }
    __syncthreads();
  }

  // y: reduce yp[j] across the 16 lanes sharing each row
#pragma unroll
  for (int j = 0; j < 8; ++j) {
    float s = yp[j];
    s += __shfl_xor(s, 1);
    s += __shfl_xor(s, 2);
    s += __shfl_xor(s, 4);
    s += __shfl_xor(s, 8);
    if ((t & 15) == 0) y[row0 + (t >> 4) + j * 16] = s;
  }

  // f epilogue (R1-verified)
  const float b2 = b2p[0];
  float w2c[4], b1c[4];
#pragma unroll
  for (int ni = 0; ni < 4; ++ni) {
    const int c = wc * 64 + ni * 16 + l15;
    w2c[ni] = w2[c];
    b1c[ni] = b1[c];
  }
  float pr[4][4];
#pragma unroll
  for (int mi = 0; mi < 4; ++mi) {
#pragma unroll
    for (int q = 0; q < 4; ++q) {
      float s = 0.f;
#pragma unroll
      for (int ni = 0; ni < 4; ++ni)
        s += w2c[ni] * tanhf(acc[mi][ni][q] + b1c[ni]);
      s += __shfl_xor(s, 1);
      s += __shfl_xor(s, 2);
      s += __shfl_xor(s, 4);
      s += __shfl_xor(s, 8);
      pr[mi][q] = s;
    }
  }
  if (wc == 1 && l15 == 0) {
#pragma unroll
    for (int mi = 0; mi < 4; ++mi)
#pragma unroll
      for (int q = 0; q < 4; ++q)
        fpart[wr * 64 + mi * 16 + lg * 4 + q] = pr[mi][q];
  }
  __syncthreads();
  if (wc == 0 && l15 == 0) {
#pragma unroll
    for (int mi = 0; mi < 4; ++mi)
#pragma unroll
      for (int q = 0; q < 4; ++q) {
        const int rl = wr * 64 + mi * 16 + lg * 4 + q;
        f[row0 + rl] = pr[mi][q] + fpart[rl] + b2;
      }
  }
}

// ---------------------------------------------------------------------------
// Kernel 2: per bag (1 block, 1024 thr):
//  (a) masked m, Z = sum exp(f-m), Sy = sum exp(f-m)*y  ->  bag_pred, crit_loss
//  (b) top/bottom-64 ids via 4-pass byte radix select (ties: lowest index)
// ---------------------------------------------------------------------------
__global__ __launch_bounds__(1024) void k_select(
    const float* __restrict__ f, const float* __restrict__ y,
    const float* __restrict__ mask, const int* __restrict__ labels,
    const float* __restrict__ bc, int* __restrict__ sel,
    float* __restrict__ out) {
  __shared__ unsigned int uv[NN];     // 64 KB, swizzled via fvx()
  __shared__ unsigned int hist[256];
  __shared__ unsigned int wq[16];
  __shared__ unsigned int sb[4];
  __shared__ float redf[16];
  const int t = threadIdx.x;
  const int lane = t & 63, w = t >> 6;
  const int b = blockIdx.x;
  const float* fb = f + (size_t)b * NN;
  const float* yb = y + (size_t)b * NN;
  const float* kb = mask + (size_t)b * NN;

  // load keys + masked max
  float mx = -3.0e38f;
  for (int i = t; i < NN; i += 1024) {
    const float v = fb[i];
    uv[fvx(i)] = ordu(v);
    mx = fmaxf(mx, kb[i] > 0.f ? v : -1.0e30f);
  }
#pragma unroll
  for (int s = 1; s < 64; s <<= 1) mx = fmaxf(mx, __shfl_xor(mx, s));
  if (lane == 0) redf[w] = mx;
  __syncthreads();
  float m = redf[0];
#pragma unroll
  for (int q = 1; q < 16; ++q) m = fmaxf(m, redf[q]);
  __syncthreads();

  // Z and Sy
  float se = 0.f, sy = 0.f;
  for (int i = t; i < NN; i += 1024) {
    if (kb[i] > 0.f) {
      const float e = expf(fb[i] - m);
      se += e;
      sy += e * yb[i];
    }
  }
#pragma unroll
  for (int s = 1; s < 64; s <<= 1) se += __shfl_xor(se, s);
  if (lane == 0) redf[w] = se;
  __syncthreads();
  float Z = 0.f;
#pragma unroll
  for (int q = 0; q < 16; ++q) Z += redf[q];
  __syncthreads();
#pragma unroll
  for (int s = 1; s < 64; s <<= 1) sy += __shfl_xor(sy, s);
  if (lane == 0) redf[w] = sy;
  __syncthreads();
  if (t == 0) {
    float Sy = 0.f;
#pragma unroll
    for (int q = 0; q < 16; ++q) Sy += redf[q];
    const float bp = Sy / Z + bc[0];
    out[b] = bp;
    const float lf = (float)labels[b];
    atomicAdd(out + 8, (softplusf(bp) - bp * lf) * 0.125f);
  }
  __syncthreads();

  // radix select (R7-verified)
  const int i0 = t * 16;
  for (int mode = 0; mode < 2; ++mode) {
    unsigned int pref = 0u, above = 0u, krem = 64u;
    for (int p = 3; p >= 0; --p) {
      if (t < 256) hist[t] = 0u;
      __syncthreads();
      const unsigned int pmask = (p == 3) ? 0u : (0xFFFFFFFFu << ((p + 1) * 8));
      for (int j = 0; j < 16; ++j) {
        unsigned int u = uv[fvx(i0 + j)];
        if (mode) u = ~u;
        if ((u & pmask) == pref)
          atomicAdd(&hist[(u >> (p * 8)) & 255u], 1u);
      }
      __syncthreads();
      unsigned int v = 0, s = 0;
      if (t < 256) {
        v = hist[t];
        s = v;
#pragma unroll
        for (int off = 1; off < 64; off <<= 1) {
          const unsigned int o = __shfl_down(s, off);
          if (lane + off < 64) s += o;
        }
        if (lane == 0) wq[w] = s;
      }
      __syncthreads();
      if (t < 256) {
        unsigned int hi = 0;
        for (int q = w + 1; q < 4; ++q) hi += wq[q];
        const unsigned int Ssuf = s + hi;
        const unsigned int Snext = Ssuf - v;
        if (Ssuf >= krem && Snext < krem) {
          sb[0] = pref | ((unsigned int)t << (p * 8));
          sb[1] = above + Snext;
          sb[2] = krem - Snext;
          sb[3] = 0u;
        }
      }
      __syncthreads();
      pref = sb[0]; above = sb[1]; krem = sb[2];
    }
    const int off = b * 128 + mode * 64;
    unsigned int myt = 0;
    for (int j = 0; j < 16; ++j) {
      unsigned int u = uv[fvx(i0 + j)];
      if (mode) u = ~u;
      if (u > pref) {
        const unsigned int pos = atomicAdd(&sb[3], 1u);
        sel[off + pos] = i0 + j;
      } else if (u == pref) {
        myt++;
      }
    }
    unsigned int pv = myt;
#pragma unroll
    for (int o2 = 1; o2 < 64; o2 <<= 1) {
      const unsigned int o = __shfl_up(pv, o2);
      if (lane >= o2) pv += o;
    }
    __syncthreads();
    if (lane == 63) wq[w] = pv;
    __syncthreads();
    unsigned int base = 0;
    for (int q = 0; q < w; ++q) base += wq[q];
    unsigned int gg = base + pv - myt;
    for (int j = 0; j < 16 && myt > 0; ++j) {
      unsigned int u = uv[fvx(i0 + j)];
      if (mode) u = ~u;
      if (u == pref) {
        if (gg < krem) sel[off + above + gg] = i0 + j;
        gg++;
        myt--;
      }
    }
    __syncthreads();
  }
}

// ---------------------------------------------------------------------------
// Kernel 3: instance smooth-top1-SVM losses (bag terms done in k_select).
// grid = 32 (bag = blk>>2, row-quarter = blk&3).
// ---------------------------------------------------------------------------
__global__ __launch_bounds__(256) void k_final(
    const float* __restrict__ X, const int* __restrict__ labels,
    const int* __restrict__ sel, const float* __restrict__ Wi,
    const float* __restrict__ bi, float* __restrict__ out) {
  const int b = blockIdx.x >> 2, part = blockIdx.x & 3;
  const int t = threadIdx.x;
  const int lane = t & 63, w = t >> 6;
  __shared__ float sin_[4], sout_[4];
  const int label = labels[b];

  const float* Win = Wi + label * (DD * 2);
  const float* Wot = Wi + (1 - label) * (DD * 2);
  const float bin0 = bi[label * 2], bin1 = bi[label * 2 + 1];
  const float bo0 = bi[(1 - label) * 2], bo1 = bi[(1 - label) * 2 + 1];
  float ain = 0.f, aout = 0.f;
  for (int ii = 0; ii < 8; ++ii) {
    const int r = part * 32 + w * 8 + ii;     // 0..127
    const int id = sel[b * 128 + r];
    const float* xr = X + ((size_t)b * NN + id) * DD;
    float p0 = 0.f, p1 = 0.f, p2 = 0.f, p3 = 0.f;
#pragma unroll
    for (int j = 0; j < 16; j += 4) {
      const int d = lane * 16 + j;
      const float4 x = *(const float4*)(xr + d);
      const float4 wa = *(const float4*)(Win + d * 2);
      const float4 wb = *(const float4*)(Win + d * 2 + 4);
      p0 += x.x * wa.x + x.y * wa.z + x.z * wb.x + x.w * wb.z;
      p1 += x.x * wa.y + x.y * wa.w + x.z * wb.y + x.w * wb.w;
      if (r < 64) {
        const float4 oa = *(const float4*)(Wot + d * 2);
        const float4 ob = *(const float4*)(Wot + d * 2 + 4);
        p2 += x.x * oa.x + x.y * oa.z + x.z * ob.x + x.w * ob.z;
        p3 += x.x * oa.y + x.y * oa.w + x.z * ob.y + x.w * ob.w;
      }
    }
#pragma unroll
    for (int sh = 1; sh < 64; sh <<= 1) {
      p0 += __shfl_xor(p0, sh);
      p1 += __shfl_xor(p1, sh);
      p2 += __shfl_xor(p2, sh);
      p3 += __shfl_xor(p3, sh);
    }
    if (lane == 0) {
      const float l0 = p0 + bin0, l1 = p1 + bin1;
      ain += (r < 64) ? softplusf(l0 + 1.f - l1) : softplusf(l1 + 1.f - l0);
      if (r < 64) aout += softplusf((p3 + bo1) + 1.f - (p2 + bo0));
    }
  }
  if (lane == 0) { sin_[w] = ain; sout_[w] = aout; }
  __syncthreads();
  if (t == 0) {
    const float ti = sin_[0] + sin_[1] + sin_[2] + sin_[3];
    const float to = sout_[0] + sout_[1] + sout_[2] + sout_[3];
    atomicAdd(out + 9, ti * (1.0f / 128.0f) + to * (1.0f / 64.0f));
  }
}

// ---------------------------------------------------------------------------

extern "C" void kernel_launch(void* const* d_in, const int* in_sizes, int n_in,
                              void* d_out, int out_size, void* d_ws, size_t ws_size,
                              hipStream_t stream) {
  const float* X      = (const float*)d_in[0];
  const float* mask   = (const float*)d_in[1];
  const int*   labels = (const int*)d_in[2];
  const float* W1     = (const float*)d_in[3];
  const float* b1     = (const float*)d_in[4];
  const float* w2     = (const float*)d_in[5];
  const float* b2     = (const float*)d_in[6];
  const float* Wc     = (const float*)d_in[7];
  const float* bc     = (const float*)d_in[8];
  const float* Wi     = (const float*)d_in[9];
  const float* bi     = (const float*)d_in[10];
  float* out = (float*)d_out;

  float* ws  = (float*)d_ws;
  float* f   = ws;                             // 131072 f32
  float* y   = ws + 131072;                    // 131072 f32
  int*   sel = (int*)(ws + 262144);            // 1024 int
  unsigned short* W1T = (unsigned short*)(ws + 263168);  // 131072 bf16

  k_prep  <<<512,  256, 0, stream>>>(W1, W1T, out);
  k_scores<<<1024, 256, 0, stream>>>(X, W1T, b1, w2, b2, Wc, f, y);
  k_select<<<8,   1024, 0, stream>>>(f, y, mask, labels, bc, sel, out);
  k_final <<<32,   256, 0, stream>>>(X, labels, sel, Wi, bi, out);
}